// Round 1
// 146.044 us; speedup vs baseline: 1.1215x; 1.1215x over previous
//
#include <hip/hip_runtime.h>
#include <stdint.h>

#define NROWS 2048
#define DDIM  9216
#define T64   32                      // max 64-row tiles per dim (2048/64)
#define NTRI  528                     // T64*(T64+1)/2 triangle tiles
#define WKLEN 2304                    // DDIM/4 : K-range per wave
#define WKIT  36                      // WKLEN/64 : K iterations per wave

typedef unsigned short u16;
typedef __bf16 bf16x8 __attribute__((ext_vector_type(8)));
typedef float  f32x4  __attribute__((ext_vector_type(4)));

// ws layout: [0] int cnt, [4] float sq, [256..) u16 nf[2048][9216] (37.75 MB)
#define NF_OFF 256

__device__ __forceinline__ u16 f2bf(float f) {
    uint32_t x = __float_as_uint(f);
    x += 0x7fffu + ((x >> 16) & 1u);          // round-to-nearest-even
    return (u16)(x >> 16);
}

__device__ __forceinline__ void gload16(const u16* g, u16* l) {
    __builtin_amdgcn_global_load_lds(
        (const __attribute__((address_space(1))) uint32_t*)g,
        (__attribute__((address_space(3))) uint32_t*)l, 16, 0, 0);
}

// ---------------- kernel 1: per-row stats + normalize + compact ----------------
__global__ __launch_bounds__(256) void stats_kernel(const float* __restrict__ wgt,
                                                    const float* __restrict__ mask,
                                                    u16* __restrict__ nf,
                                                    int* __restrict__ cnt) {
    int n = blockIdx.x;
    if (mask[n] == 0.0f) return;              // inactive filter: skip entirely
    int tid = threadIdx.x;
    const float4* row = (const float4*)(wgt + (size_t)n * DDIM);
    float4 v[9];
    float s = 0.f, ss = 0.f;
#pragma unroll
    for (int i = 0; i < 9; ++i) {
        v[i] = row[tid + 256 * i];
        s  += v[i].x + v[i].y + v[i].z + v[i].w;
        ss += v[i].x * v[i].x + v[i].y * v[i].y + v[i].z * v[i].z + v[i].w * v[i].w;
    }
#pragma unroll
    for (int o = 32; o > 0; o >>= 1) { s += __shfl_down(s, o); ss += __shfl_down(ss, o); }
    __shared__ float rs[4], rss[4];
    __shared__ float smean, sinv;
    __shared__ int   sidx;
    int w = tid >> 6, l = tid & 63;
    if (l == 0) { rs[w] = s; rss[w] = ss; }
    __syncthreads();
    if (tid == 0) {
        float S  = rs[0] + rs[1] + rs[2] + rs[3];
        float SS = rss[0] + rss[1] + rss[2] + rss[3];
        float mean = S / (float)DDIM;
        float var  = SS / (float)DDIM - mean * mean;
        float sd   = sqrtf(fmaxf(var, 0.f));
        if (sd == 0.f) sd = 1.f;              // reference: std==0 -> 1
        smean = mean; sinv = 1.f / sd;
        sidx = atomicAdd(cnt, 1);             // compacted slot (order irrelevant)
    }
    __syncthreads();
    float mean = smean, inv = sinv;
    u16* dst = nf + (size_t)sidx * DDIM;
#pragma unroll
    for (int i = 0; i < 9; ++i) {
        int e = (tid + 256 * i) * 4;
        uint32_t lo = (uint32_t)f2bf((v[i].x - mean) * inv) |
                      ((uint32_t)f2bf((v[i].y - mean) * inv) << 16);
        uint32_t hi = (uint32_t)f2bf((v[i].z - mean) * inv) |
                      ((uint32_t)f2bf((v[i].w - mean) * inv) << 16);
        uint2 u; u.x = lo; u.y = hi;
        *(uint2*)(dst + e) = u;
    }
}

// ---------------- kernel 2: fused 64x64-tile GEMM + square-reduce ----------------
// Block = 4 waves, each owning a PRIVATE K-quarter with PRIVATE double-buffered
// LDS (2 x (A 8KB + B 8KB) per wave = 128 KB/block). No __syncthreads in the
// K-loop. Pipeline: issue stage(it+1) into alt buffer, s_waitcnt vmcnt(16)
// (counted, never 0 mid-loop) so stage(it)'s DMA latency overlaps compute.
// LDS XOR swizzle: row stride is 128 B (= 32 banks), so physical 16B chunk
// = logical chunk ^ (row&7). Applied on the GLOBAL source address (DMA dest
// stays linear, rule #21) and on the ds_read offset.
template<bool DIAG>
__device__ __forceinline__ void kstep(const u16* pA, const u16* pB, int it,
                                      u16* Ac, u16* An, u16* Bc, u16* Bn,
                                      int m16, int sw0, f32x4 acc[4][4]) {
    if (it + 1 < WKIT) {
        const u16* a = pA + (it + 1) * 64;
#pragma unroll
        for (int i = 0; i < 8; ++i) gload16(a + i * 8 * DDIM, An + i * 512);
        if (!DIAG) {
            const u16* b = pB + (it + 1) * 64;
#pragma unroll
            for (int i = 0; i < 8; ++i) gload16(b + i * 8 * DDIM, Bn + i * 512);
        }
        // wait for stage(it) only: the 8/16 loads just issued stay in flight.
        __builtin_amdgcn_s_waitcnt(DIAG ? 0x0F78 : 0x4F70);  // vmcnt(8)/vmcnt(16)
    } else {
        __builtin_amdgcn_s_waitcnt(0x0F70);                  // last iter: vmcnt(0)
    }
    __builtin_amdgcn_wave_barrier();
    const u16* rB = DIAG ? Ac : Bc;
#pragma unroll
    for (int kk = 0; kk < 2; ++kk) {
        int sw = sw0 ^ (kk << 5);             // swizzled byte-chunk for this K-half
        bf16x8 af[4], bfr[4];
#pragma unroll
        for (int fm = 0; fm < 4; ++fm)
            af[fm] = *(const bf16x8*)&Ac[(fm * 16 + m16) * 64 + sw];
#pragma unroll
        for (int fn = 0; fn < 4; ++fn)
            bfr[fn] = *(const bf16x8*)&rB[(fn * 16 + m16) * 64 + sw];
#pragma unroll
        for (int fm = 0; fm < 4; ++fm)
#pragma unroll
            for (int fn = 0; fn < 4; ++fn)
                acc[fm][fn] = __builtin_amdgcn_mfma_f32_16x16x32_bf16(
                    af[fm], bfr[fn], acc[fm][fn], 0, 0, 0);
    }
    __builtin_amdgcn_wave_barrier();          // keep next stage's DMA after reads
}

__global__ __launch_bounds__(256) void gemm_kernel(const u16* __restrict__ nf,
                                                   const int* __restrict__ cnt,
                                                   float* __restrict__ sq) {
    __shared__ u16 ls[65536];                 // 128 KB: 4 waves x 2 x (A 8KB + B 8KB)
    int A = *cnt;
    int nt = (A + 63) >> 6;
    int t = blockIdx.x, bi = 0, len = T64;
    while (t >= len) { t -= len; --len; ++bi; }
    int bj = bi + t;
    if (bj >= nt) return;                     // bi <= bj
    int r0 = bi << 6, c0 = bj << 6;
    int tid = threadIdx.x, l = tid & 63, w = tid >> 6;
    int quad = l >> 4, m16 = l & 15;
    int kbeg = w * WKLEN;
    // pre-swizzled global column chunk: lane l fetches logical chunk
    // (l&7)^(l>>3) so linear DMA lands it at physical chunk (l&7) of row (l>>3).
    int colsw = ((l & 7) ^ (l >> 3)) << 3;
    const u16* pA = nf + (size_t)(r0 + (l >> 3)) * DDIM + colsw + kbeg;
    const u16* pB = nf + (size_t)(c0 + (l >> 3)) * DDIM + colsw + kbeg;
    u16* base = ls + w * 16384;               // 32 KB per wave
    u16* A0 = base,        *A1 = base + 4096;
    u16* B0 = base + 8192, *B1 = base + 12288;
    int sw0 = (quad ^ (m16 & 7)) << 3;        // swizzled ds_read chunk, kk=0
    f32x4 acc[4][4] = {};
    if (bi == bj) {
#pragma unroll
        for (int i = 0; i < 8; ++i) gload16(pA + i * 8 * DDIM, A0 + i * 512);
        for (int it = 0; it < WKIT; it += 2) {
            kstep<true >(pA, pB, it,     A0, A1, B0, B1, m16, sw0, acc);
            kstep<true >(pA, pB, it + 1, A1, A0, B1, B0, m16, sw0, acc);
        }
    } else {
#pragma unroll
        for (int i = 0; i < 8; ++i) gload16(pA + i * 8 * DDIM, A0 + i * 512);
#pragma unroll
        for (int i = 0; i < 8; ++i) gload16(pB + i * 8 * DDIM, B0 + i * 512);
        for (int it = 0; it < WKIT; it += 2) {
            kstep<false>(pA, pB, it,     A0, A1, B0, B1, m16, sw0, acc);
            kstep<false>(pA, pB, it + 1, A1, A0, B1, B0, m16, sw0, acc);
        }
    }

    // ---- epilogue: park partials in own wave's LDS region (frag-major) ----
    float* fw = (float*)ls + w * 8192;        // own 32 KB region base; use 16 KB
#pragma unroll
    for (int fm = 0; fm < 4; ++fm)
#pragma unroll
        for (int fn = 0; fn < 4; ++fn)
            *(f32x4*)&fw[(fm * 4 + fn) * 256 + l * 4] = acc[fm][fn];
    __syncthreads();
    const float* fs = (const float*)ls;
    float local = 0.f;
#pragma unroll
    for (int i = 0; i < 4; ++i) {
        int o = tid * 4 + i * 1024;           // offset within a parked 16 KB block
        f32x4 v = *(const f32x4*)&fs[o];
        v += *(const f32x4*)&fs[o + 8192];    // wave regions are 8192 floats apart
        v += *(const f32x4*)&fs[o + 16384];
        v += *(const f32x4*)&fs[o + 24576];
        int f = o >> 8, lk = (o >> 2) & 63;   // frag id, lane id; o&3 = reg r
        int row = ((f >> 2) << 4) + ((lk >> 4) << 2);   // + r
        int col = ((f & 3) << 4) + (lk & 15);
        int gj = c0 + col;
        if (gj < A) {
#pragma unroll
            for (int r = 0; r < 4; ++r) {
                int gi = r0 + row + r;
                if (gi < gj) local += v[r] * v[r];
            }
        }
    }
#pragma unroll
    for (int o = 32; o > 0; o >>= 1) local += __shfl_down(local, o);
    if (l == 0) atomicAdd(sq, local);         // 4 atomics per active block
}

// ---------------- kernel 3: finalize ----------------
__global__ void final_kernel(const int* __restrict__ cnt, const float* __restrict__ sq,
                             float* __restrict__ out) {
    long long A = *cnt;
    long long na = A * (A - 1) / 2;           // sum of strict-upper mask products
    double loss = 0.0;
    if (na > 0) loss = (double)(*sq) / ((double)DDIM * (double)DDIM) / (double)na;
    out[0] = (float)loss;
}

extern "C" void kernel_launch(void* const* d_in, const int* in_sizes, int n_in,
                              void* d_out, int out_size, void* d_ws, size_t ws_size,
                              hipStream_t stream) {
    (void)in_sizes; (void)n_in; (void)out_size; (void)ws_size;
    const float* wgt  = (const float*)d_in[0];
    const float* mask = (const float*)d_in[1];
    float* out = (float*)d_out;
    char*  ws  = (char*)d_ws;

    int*   cnt = (int*)ws;
    float* sq  = (float*)(ws + 4);
    u16*   nf  = (u16*)(ws + NF_OFF);

    hipMemsetAsync(ws, 0, 256, stream);
    stats_kernel<<<NROWS, 256, 0, stream>>>(wgt, mask, nf, cnt);
    gemm_kernel<<<NTRI, 256, 0, stream>>>(nf, cnt, sq);
    final_kernel<<<1, 1, 0, stream>>>(cnt, sq, out);
}